// Round 9
// baseline (189.797 us; speedup 1.0000x reference)
//
#include <hip/hip_runtime.h>
#include <hip/hip_bf16.h>

// GCN layer, algebraically refactored:
//   hs[n]  = (x[n] @ W) * dis[n],   dis[n] = rsqrt(1 + sum_{e: col=n} w[e])
//   out[n] = relu( dis[n] * ( hs[n] + sum_{e: col=n} w[e] * hs[row[e]] ) + bias )
// Identical to PyG GCNConv (self-loops, symmetric norm) + ReLU.
// hs stored bf16; GEMM bf16 MFMA (fp32 accumulate); pull-based CSR aggregation
// with wave-prefetched edge records (breaks the record->gather dependent-load
// chain: one coalesced 512B record load + __shfl broadcast, gathers issue
// back-to-back). CSR via 2-pass radix partition (256-node buckets).

#define IN_C 128
#define HID_C 128
#define CAP 6144          // per-bucket edge capacity (mean 4082, +32 sigma)
#define EPB 4096          // edges per pass-A block (16 per thread; 196 blocks)

typedef __attribute__((ext_vector_type(8))) short bf16x8;
typedef __attribute__((ext_vector_type(4))) float f32x4;

// ---------- bf16 helpers (manual RNE) ----------
__device__ inline unsigned f2bf(float f) {
    unsigned u = __float_as_uint(f);
    return (u + 0x7FFFu + ((u >> 16) & 1u)) >> 16;
}
__device__ inline float bf_lo(unsigned v) { return __uint_as_float(v << 16); }
__device__ inline float bf_hi(unsigned v) { return __uint_as_float(v & 0xFFFF0000u); }

// ---------- prep: W -> bf16 W^T, pre-swizzled; block 0 also zeroes gcur ----------
__global__ __launch_bounds__(256) void k_prepW(const float* __restrict__ W,
                                               unsigned short* __restrict__ wt,
                                               int* __restrict__ gcur) {
    const int t = threadIdx.x;
    if (blockIdx.x == 0) gcur[t] = 0;
    int i = blockIdx.x * 256 + t;          // 0..4095
    int n = i & 127;
    int k0 = (i >> 7) * 4;
    ushort4 bv;
    bv.x = (unsigned short)f2bf(W[(size_t)(k0 + 0) * HID_C + n]);
    bv.y = (unsigned short)f2bf(W[(size_t)(k0 + 1) * HID_C + n]);
    bv.z = (unsigned short)f2bf(W[(size_t)(k0 + 2) * HID_C + n]);
    bv.w = (unsigned short)f2bf(W[(size_t)(k0 + 3) * HID_C + n]);
    int idx = (n * 128 + k0) ^ ((n & 7) << 3);   // ushort-index swizzle
    *(ushort4*)&wt[idx] = bv;
}

// ---------- pass A: radix partition edges into 256-node buckets ----------
__global__ __launch_bounds__(256) void k_passA(const int* __restrict__ row,
                                               const int* __restrict__ col,
                                               const float* __restrict__ w,
                                               int* __restrict__ gcur,
                                               int2* __restrict__ bedge,
                                               int E, int NBK) {
    __shared__ int hist[256], base_s[256], cur[256];
    const int t = threadIdx.x;
    const int e0 = blockIdx.x * EPB;
    const int e1 = min(E, e0 + EPB);

    hist[t] = 0;
    __syncthreads();

    int cbuf[EPB / 256];
    #pragma unroll
    for (int i = 0; i < EPB / 256; ++i) {
        int e = e0 + t + i * 256;
        int c = (e < e1) ? col[e] : -1;
        cbuf[i] = c;
        if (c >= 0) atomicAdd(&hist[c >> 8], 1);
    }
    __syncthreads();

    if (t < NBK && hist[t] > 0) base_s[t] = atomicAdd(&gcur[t], hist[t]);
    cur[t] = 0;
    __syncthreads();

    #pragma unroll
    for (int i = 0; i < EPB / 256; ++i) {
        int c = cbuf[i];
        if (c >= 0) {
            int e = e0 + t + i * 256;
            int b = c >> 8;
            int lpos = atomicAdd(&cur[b], 1);
            int2 rec;
            rec.x = ((c & 255) << 24) | row[e];   // col_local | row (row < 2^24)
            rec.y = __float_as_int(w[e]);
            bedge[(size_t)b * CAP + base_s[b] + lpos] = rec;
        }
    }
}

// ---------- pass B: per-bucket — bucket scan, degree, dis, CSR ptr, placement ----------
__global__ __launch_bounds__(256) void k_passB(const int2* __restrict__ bedge,
                                               const int* __restrict__ gcur,
                                               int2* __restrict__ sedge,
                                               int* __restrict__ ptr,
                                               float* __restrict__ dis,
                                               int E, int N, int NBK) {
    __shared__ float wdeg[256];
    __shared__ int cnt[256], cur[256], sm[256], ebs[256], cnts[256];
    const int b = blockIdx.x;
    const int t = threadIdx.x;
    const int nb0 = b << 8;

    // redundant per-block exclusive scan of bucket counts -> edge base
    int gv = (t < NBK) ? gcur[t] : 0;
    int gs = gv;
    sm[t] = gs;
    __syncthreads();
    for (int off = 1; off < 256; off <<= 1) {
        int add = (t >= off) ? sm[t - off] : 0;
        __syncthreads();
        gs += add;
        sm[t] = gs;
        __syncthreads();
    }
    ebs[t] = gs - gv;
    cnts[t] = gv;
    wdeg[t] = 0.f;
    cnt[t] = 0;
    __syncthreads();

    const int ecnt = cnts[b];
    const int eb   = ebs[b];
    const int2* be = bedge + (size_t)b * CAP;
    if (b == 0 && t == 0) ptr[N] = E;

    for (int p = t; p < ecnt; p += 256) {
        int2 rec = be[p];
        int cl = (rec.x >> 24) & 255;
        atomicAdd(&cnt[cl], 1);
        atomicAdd(&wdeg[cl], __int_as_float(rec.y));   // LDS f32 atomic
    }
    __syncthreads();

    // exclusive scan of per-node counts
    int v = cnt[t];
    int s = v;
    sm[t] = s;
    __syncthreads();
    for (int off = 1; off < 256; off <<= 1) {
        int add = (t >= off) ? sm[t - off] : 0;
        __syncthreads();
        s += add;
        sm[t] = s;
        __syncthreads();
    }
    int excl = s - v;
    cur[t] = excl;
    int n = nb0 + t;
    if (n < N) {
        dis[n] = rsqrtf(1.0f + wdeg[t]);
        ptr[n] = eb + excl;
    }
    __syncthreads();

    for (int p = t; p < ecnt; p += 256) {
        int2 rec = be[p];
        int cl = (rec.x >> 24) & 255;
        int lpos = atomicAdd(&cur[cl], 1);
        int2 o;
        o.x = rec.x & 0xFFFFFF;
        o.y = rec.y;
        sedge[eb + lpos] = o;
    }
}

// ---------- MFMA GEMM: hs(bf16) = (x @ W) * dis ----------
// 64 rows/block, full 128 cols. 4 waves; wave w owns rows [w*16, w*16+16).
// LDS: x tile bf16 [64][128] (converted here), W^T bf16 [128][128] copied
// linearly from pre-swizzled wt. Both XOR-swizzled (ushort idx ^= (row&7)<<3).
__global__ __launch_bounds__(256) void k_gemm_hs(const float* __restrict__ x,
                                                 const unsigned short* __restrict__ wt,
                                                 const float* __restrict__ dis,
                                                 unsigned short* __restrict__ hsb, int N) {
    __shared__ __align__(16) unsigned short xsb[64 * 128];    // 16 KB
    __shared__ __align__(16) unsigned short wsb[128 * 128];   // 32 KB

    const int t = threadIdx.x;
    const int base = blockIdx.x * 64;

    // stage W^T: linear 16B copies, swizzle already applied in global source
    for (int i = t; i < (128 * 128) / 8; i += 256)
        ((uint4*)wsb)[i] = ((const uint4*)wt)[i];

    // stage x tile: xsb[r][k] = bf16(x[base+r][k]); coalesced float4 reads
    for (int i = t; i < 64 * 32; i += 256) {
        int r = i >> 5;
        int c4 = (i & 31) * 4;
        int gr = base + r;
        if (gr >= N) gr = N - 1;
        float4 v = *(const float4*)&x[(size_t)gr * IN_C + c4];
        ushort4 bv;
        bv.x = (unsigned short)f2bf(v.x);
        bv.y = (unsigned short)f2bf(v.y);
        bv.z = (unsigned short)f2bf(v.z);
        bv.w = (unsigned short)f2bf(v.w);
        int idx = (r * 128 + c4) ^ ((r & 7) << 3);
        *(ushort4*)&xsb[idx] = bv;
    }
    __syncthreads();

    const int w  = t >> 6;
    const int l  = t & 63;
    const int lr = l & 15;            // A row / B col within 16
    const int lk = (l >> 4) * 8;      // k offset within 32

    f32x4 acc[8];
    #pragma unroll
    for (int nt = 0; nt < 8; ++nt) acc[nt] = (f32x4){0.f, 0.f, 0.f, 0.f};

    #pragma unroll
    for (int ks = 0; ks < 4; ++ks) {
        int k0 = ks * 32 + lk;
        int arow = w * 16 + lr;
        bf16x8 a = *(const bf16x8*)&xsb[(arow * 128 + k0) ^ ((arow & 7) << 3)];
        #pragma unroll
        for (int nt = 0; nt < 8; ++nt) {
            int bn = nt * 16 + lr;
            bf16x8 bb = *(const bf16x8*)&wsb[(bn * 128 + k0) ^ ((bn & 7) << 3)];
            acc[nt] = __builtin_amdgcn_mfma_f32_16x16x32_bf16(a, bb, acc[nt], 0, 0, 0);
        }
    }

    // epilogue: D row = (l>>4)*4 + j, col = nt*16 + lr (m89-verified layout)
    const int mbase = base + w * 16 + (l >> 4) * 4;
    float d[4];
    #pragma unroll
    for (int j = 0; j < 4; ++j)
        d[j] = (mbase + j < N) ? dis[mbase + j] : 0.f;
    #pragma unroll
    for (int nt = 0; nt < 8; ++nt) {
        int c = nt * 16 + lr;
        #pragma unroll
        for (int j = 0; j < 4; ++j) {
            int n = mbase + j;
            if (n < N)
                hsb[(size_t)n * HID_C + c] = (unsigned short)f2bf(acc[nt][j] * d[j]);
        }
    }
}

// ---------- pull aggregation: one wave per node ----------
// Edge records prefetched 64-at-a-time in ONE coalesced 512B wave load, then
// broadcast per edge via __shfl — gathers issue back-to-back (no dependent
// global-load chain per edge).
__global__ __launch_bounds__(256) void k_aggregate(const unsigned int* __restrict__ hsb,
                                                   const int2* __restrict__ sedge,
                                                   const int* __restrict__ ptr,
                                                   const float* __restrict__ dis,
                                                   const float* __restrict__ bias,
                                                   float* __restrict__ out, int N) {
    int t = threadIdx.x;
    int n = blockIdx.x * 4 + (t >> 6);
    if (n >= N) return;
    int lane = t & 63;                 // channels 2*lane, 2*lane+1

    int start = ptr[n];
    int end   = ptr[n + 1];

    unsigned sv = hsb[(size_t)n * (HID_C / 2) + lane];   // self term
    float2 acc = { bf_lo(sv), bf_hi(sv) };

    for (int s0 = start; s0 < end; s0 += 64) {
        int cnt = min(64, end - s0);
        int2 myrec = (lane < cnt) ? sedge[s0 + lane] : make_int2(0, 0);
        #pragma unroll 8
        for (int i = 0; i < cnt; ++i) {
            int   r  = __shfl(myrec.x, i);
            float wt = __int_as_float(__shfl(myrec.y, i));
            unsigned v = hsb[(size_t)r * (HID_C / 2) + lane];
            acc.x = fmaf(wt, bf_lo(v), acc.x);
            acc.y = fmaf(wt, bf_hi(v), acc.y);
        }
    }

    float d = dis[n];
    float2 bv = ((const float2*)bias)[lane];
    float2 o;
    o.x = fmaxf(fmaf(d, acc.x, bv.x), 0.f);
    o.y = fmaxf(fmaf(d, acc.y, bv.y), 0.f);
    ((float2*)(out + (size_t)n * HID_C))[lane] = o;
}

extern "C" void kernel_launch(void* const* d_in, const int* in_sizes, int n_in,
                              void* d_out, int out_size, void* d_ws, size_t ws_size,
                              hipStream_t stream) {
    const float* x    = (const float*)d_in[0];
    const int*   ei   = (const int*)d_in[1];
    const float* w    = (const float*)d_in[2];
    const float* W    = (const float*)d_in[3];
    const float* bias = (const float*)d_in[4];
    float* out = (float*)d_out;

    const int N = in_sizes[0] / IN_C;
    const int E = in_sizes[2];
    const int* row = ei;        // edge_index[0] (source)
    const int* col = ei + E;    // edge_index[1] (destination)
    const int NBK = (N + 255) >> 8;   // 196 buckets of 256 nodes

    // workspace: gcur[256] | ptr[N+1] | dis[N] | wt[16384] ushort
    //            | bedge[NBK*CAP] int2 | sedge[E] int2 | hsb[N*128] ushort
    auto alup = [](size_t v) { return (v + 255) & ~(size_t)255; };
    char* p = (char*)d_ws;
    int*   gcur  = (int*)p;   p += alup(256 * 4);
    int*   ptr   = (int*)p;   p += alup(((size_t)N + 1) * 4);
    float* dis   = (float*)p; p += alup((size_t)N * 4);
    unsigned short* wt = (unsigned short*)p; p += alup(16384 * 2);
    int2*  bedge = (int2*)p;  p += alup((size_t)NBK * CAP * 8);
    int2*  sedge = (int2*)p;  p += alup((size_t)E * 8);
    unsigned short* hsb = (unsigned short*)p; p += alup((size_t)N * HID_C * 2);

    k_prepW<<<16, 256, 0, stream>>>(W, wt, gcur);

    k_passA<<<(E + EPB - 1) / EPB, 256, 0, stream>>>(row, col, w, gcur, bedge, E, NBK);
    k_passB<<<NBK, 256, 0, stream>>>(bedge, gcur, sedge, ptr, dis, E, N, NBK);

    k_gemm_hs<<<(N + 63) / 64, 256, 0, stream>>>(x, wt, dis, hsb, N);

    k_aggregate<<<(N + 3) / 4, 256, 0, stream>>>((const unsigned int*)hsb, sedge, ptr,
                                                 dis, bias, out, N);
}

// Round 10
// 167.168 us; speedup vs baseline: 1.1354x; 1.1354x over previous
//
#include <hip/hip_runtime.h>
#include <hip/hip_bf16.h>

// GCN layer, algebraically refactored:
//   hs[n]  = (x[n] @ W) * dis[n],   dis[n] = rsqrt(1 + sum_{e: col=n} w[e])
//   out[n] = relu( dis[n] * ( hs[n] + sum_{e: col=n} w[e] * hs[row[e]] ) + bias )
// Identical to PyG GCNConv (self-loops, symmetric norm) + ReLU.
// hs stored bf16; GEMM bf16 MFMA (fp32 accumulate); pull-based CSR aggregation.
// Aggregate: 4 slots x 16 lanes per wave -> 4 independent rec->gather->fma
// chains per wave (hs is L2-resident; kernel is gather-LATENCY-bound, proven
// by warm-replay dur == cold dur in round 9). No shfl in the per-edge path.
// CSR via 2-pass radix partition (256-node buckets).

#define IN_C 128
#define HID_C 128
#define CAP 6144          // per-bucket edge capacity (mean 4082, +32 sigma)
#define EPB 4096          // edges per pass-A block (16 per thread; 196 blocks)

typedef __attribute__((ext_vector_type(8))) short bf16x8;
typedef __attribute__((ext_vector_type(4))) float f32x4;

// ---------- bf16 helpers (manual RNE) ----------
__device__ inline unsigned f2bf(float f) {
    unsigned u = __float_as_uint(f);
    return (u + 0x7FFFu + ((u >> 16) & 1u)) >> 16;
}
__device__ inline float bf_lo(unsigned v) { return __uint_as_float(v << 16); }
__device__ inline float bf_hi(unsigned v) { return __uint_as_float(v & 0xFFFF0000u); }

// ---------- prep: W -> bf16 W^T, pre-swizzled; block 0 also zeroes gcur ----------
__global__ __launch_bounds__(256) void k_prepW(const float* __restrict__ W,
                                               unsigned short* __restrict__ wt,
                                               int* __restrict__ gcur) {
    const int t = threadIdx.x;
    if (blockIdx.x == 0) gcur[t] = 0;
    int i = blockIdx.x * 256 + t;          // 0..4095
    int n = i & 127;
    int k0 = (i >> 7) * 4;
    ushort4 bv;
    bv.x = (unsigned short)f2bf(W[(size_t)(k0 + 0) * HID_C + n]);
    bv.y = (unsigned short)f2bf(W[(size_t)(k0 + 1) * HID_C + n]);
    bv.z = (unsigned short)f2bf(W[(size_t)(k0 + 2) * HID_C + n]);
    bv.w = (unsigned short)f2bf(W[(size_t)(k0 + 3) * HID_C + n]);
    int idx = (n * 128 + k0) ^ ((n & 7) << 3);   // ushort-index swizzle
    *(ushort4*)&wt[idx] = bv;
}

// ---------- pass A: radix partition edges into 256-node buckets ----------
__global__ __launch_bounds__(256) void k_passA(const int* __restrict__ row,
                                               const int* __restrict__ col,
                                               const float* __restrict__ w,
                                               int* __restrict__ gcur,
                                               int2* __restrict__ bedge,
                                               int E, int NBK) {
    __shared__ int hist[256], base_s[256], cur[256];
    const int t = threadIdx.x;
    const int e0 = blockIdx.x * EPB;
    const int e1 = min(E, e0 + EPB);

    hist[t] = 0;
    __syncthreads();

    int cbuf[EPB / 256];
    #pragma unroll
    for (int i = 0; i < EPB / 256; ++i) {
        int e = e0 + t + i * 256;
        int c = (e < e1) ? col[e] : -1;
        cbuf[i] = c;
        if (c >= 0) atomicAdd(&hist[c >> 8], 1);
    }
    __syncthreads();

    if (t < NBK && hist[t] > 0) base_s[t] = atomicAdd(&gcur[t], hist[t]);
    cur[t] = 0;
    __syncthreads();

    #pragma unroll
    for (int i = 0; i < EPB / 256; ++i) {
        int c = cbuf[i];
        if (c >= 0) {
            int e = e0 + t + i * 256;
            int b = c >> 8;
            int lpos = atomicAdd(&cur[b], 1);
            int2 rec;
            rec.x = ((c & 255) << 24) | row[e];   // col_local | row (row < 2^24)
            rec.y = __float_as_int(w[e]);
            bedge[(size_t)b * CAP + base_s[b] + lpos] = rec;
        }
    }
}

// ---------- pass B: per-bucket — bucket scan, degree, dis, CSR ptr, placement ----------
__global__ __launch_bounds__(256) void k_passB(const int2* __restrict__ bedge,
                                               const int* __restrict__ gcur,
                                               int2* __restrict__ sedge,
                                               int* __restrict__ ptr,
                                               float* __restrict__ dis,
                                               int E, int N, int NBK) {
    __shared__ float wdeg[256];
    __shared__ int cnt[256], cur[256], sm[256], ebs[256], cnts[256];
    const int b = blockIdx.x;
    const int t = threadIdx.x;
    const int nb0 = b << 8;

    // redundant per-block exclusive scan of bucket counts -> edge base
    int gv = (t < NBK) ? gcur[t] : 0;
    int gs = gv;
    sm[t] = gs;
    __syncthreads();
    for (int off = 1; off < 256; off <<= 1) {
        int add = (t >= off) ? sm[t - off] : 0;
        __syncthreads();
        gs += add;
        sm[t] = gs;
        __syncthreads();
    }
    ebs[t] = gs - gv;
    cnts[t] = gv;
    wdeg[t] = 0.f;
    cnt[t] = 0;
    __syncthreads();

    const int ecnt = cnts[b];
    const int eb   = ebs[b];
    const int2* be = bedge + (size_t)b * CAP;
    if (b == 0 && t == 0) ptr[N] = E;

    for (int p = t; p < ecnt; p += 256) {
        int2 rec = be[p];
        int cl = (rec.x >> 24) & 255;
        atomicAdd(&cnt[cl], 1);
        atomicAdd(&wdeg[cl], __int_as_float(rec.y));   // LDS f32 atomic
    }
    __syncthreads();

    // exclusive scan of per-node counts
    int v = cnt[t];
    int s = v;
    sm[t] = s;
    __syncthreads();
    for (int off = 1; off < 256; off <<= 1) {
        int add = (t >= off) ? sm[t - off] : 0;
        __syncthreads();
        s += add;
        sm[t] = s;
        __syncthreads();
    }
    int excl = s - v;
    cur[t] = excl;
    int n = nb0 + t;
    if (n < N) {
        dis[n] = rsqrtf(1.0f + wdeg[t]);
        ptr[n] = eb + excl;
    }
    __syncthreads();

    for (int p = t; p < ecnt; p += 256) {
        int2 rec = be[p];
        int cl = (rec.x >> 24) & 255;
        int lpos = atomicAdd(&cur[cl], 1);
        int2 o;
        o.x = rec.x & 0xFFFFFF;
        o.y = rec.y;
        sedge[eb + lpos] = o;
    }
}

// ---------- MFMA GEMM: hs(bf16) = (x @ W) * dis ----------
// 64 rows/block, full 128 cols. 4 waves; wave w owns rows [w*16, w*16+16).
// LDS: x tile bf16 [64][128] (converted here), W^T bf16 [128][128] copied
// linearly from pre-swizzled wt. Both XOR-swizzled (ushort idx ^= (row&7)<<3).
__global__ __launch_bounds__(256) void k_gemm_hs(const float* __restrict__ x,
                                                 const unsigned short* __restrict__ wt,
                                                 const float* __restrict__ dis,
                                                 unsigned short* __restrict__ hsb, int N) {
    __shared__ __align__(16) unsigned short xsb[64 * 128];    // 16 KB
    __shared__ __align__(16) unsigned short wsb[128 * 128];   // 32 KB

    const int t = threadIdx.x;
    const int base = blockIdx.x * 64;

    // stage W^T: linear 16B copies, swizzle already applied in global source
    for (int i = t; i < (128 * 128) / 8; i += 256)
        ((uint4*)wsb)[i] = ((const uint4*)wt)[i];

    // stage x tile: xsb[r][k] = bf16(x[base+r][k]); coalesced float4 reads
    for (int i = t; i < 64 * 32; i += 256) {
        int r = i >> 5;
        int c4 = (i & 31) * 4;
        int gr = base + r;
        if (gr >= N) gr = N - 1;
        float4 v = *(const float4*)&x[(size_t)gr * IN_C + c4];
        ushort4 bv;
        bv.x = (unsigned short)f2bf(v.x);
        bv.y = (unsigned short)f2bf(v.y);
        bv.z = (unsigned short)f2bf(v.z);
        bv.w = (unsigned short)f2bf(v.w);
        int idx = (r * 128 + c4) ^ ((r & 7) << 3);
        *(ushort4*)&xsb[idx] = bv;
    }
    __syncthreads();

    const int w  = t >> 6;
    const int l  = t & 63;
    const int lr = l & 15;            // A row / B col within 16
    const int lk = (l >> 4) * 8;      // k offset within 32

    f32x4 acc[8];
    #pragma unroll
    for (int nt = 0; nt < 8; ++nt) acc[nt] = (f32x4){0.f, 0.f, 0.f, 0.f};

    #pragma unroll
    for (int ks = 0; ks < 4; ++ks) {
        int k0 = ks * 32 + lk;
        int arow = w * 16 + lr;
        bf16x8 a = *(const bf16x8*)&xsb[(arow * 128 + k0) ^ ((arow & 7) << 3)];
        #pragma unroll
        for (int nt = 0; nt < 8; ++nt) {
            int bn = nt * 16 + lr;
            bf16x8 bb = *(const bf16x8*)&wsb[(bn * 128 + k0) ^ ((bn & 7) << 3)];
            acc[nt] = __builtin_amdgcn_mfma_f32_16x16x32_bf16(a, bb, acc[nt], 0, 0, 0);
        }
    }

    // epilogue: D row = (l>>4)*4 + j, col = nt*16 + lr (m89-verified layout)
    const int mbase = base + w * 16 + (l >> 4) * 4;
    float d[4];
    #pragma unroll
    for (int j = 0; j < 4; ++j)
        d[j] = (mbase + j < N) ? dis[mbase + j] : 0.f;
    #pragma unroll
    for (int nt = 0; nt < 8; ++nt) {
        int c = nt * 16 + lr;
        #pragma unroll
        for (int j = 0; j < 4; ++j) {
            int n = mbase + j;
            if (n < N)
                hsb[(size_t)n * HID_C + c] = (unsigned short)f2bf(acc[nt][j] * d[j]);
        }
    }
}

// ---------- pull aggregation: one wave per node, 4 edge-slots x 16 lanes ----------
// Slot s (lanes s*16..s*16+15) processes edge p0+s: its 16 lanes read the full
// 256B hs row as uint4 (8 ch/lane). 4 independent load chains per wave; edge
// record loads are 16-lane-uniform (HW broadcast). Slots combined once per
// node via shfl_xor(16/32); lanes 0..15 finalize and write the row.
__global__ __launch_bounds__(256) void k_aggregate(const uint4* __restrict__ hsb4,
                                                   const int2* __restrict__ sedge,
                                                   const int* __restrict__ ptr,
                                                   const float* __restrict__ dis,
                                                   const float* __restrict__ bias,
                                                   float* __restrict__ out, int N) {
    int t = threadIdx.x;
    int n = blockIdx.x * 4 + (t >> 6);
    if (n >= N) return;
    int lane = t & 63;
    int slot = lane >> 4;      // 0..3: edge slot
    int cl   = lane & 15;      // 16B chunk within the 256B row -> channels cl*8..cl*8+7

    int start = ptr[n];
    int end   = ptr[n + 1];

    float acc[8];
    #pragma unroll
    for (int j = 0; j < 8; ++j) acc[j] = 0.f;

    #pragma unroll 2
    for (int p0 = start; p0 < end; p0 += 4) {
        int p = p0 + slot;
        int2 rec = (p < end) ? sedge[p] : make_int2(n, 0);   // wt=0 pad
        float wt = __int_as_float(rec.y);
        uint4 v = hsb4[(size_t)rec.x * 16 + cl];
        acc[0] = fmaf(wt, bf_lo(v.x), acc[0]);
        acc[1] = fmaf(wt, bf_hi(v.x), acc[1]);
        acc[2] = fmaf(wt, bf_lo(v.y), acc[2]);
        acc[3] = fmaf(wt, bf_hi(v.y), acc[3]);
        acc[4] = fmaf(wt, bf_lo(v.z), acc[4]);
        acc[5] = fmaf(wt, bf_hi(v.z), acc[5]);
        acc[6] = fmaf(wt, bf_lo(v.w), acc[6]);
        acc[7] = fmaf(wt, bf_hi(v.w), acc[7]);
    }

    // combine the 4 slots (same cl across slots -> butterfly over ^16, ^32)
    #pragma unroll
    for (int j = 0; j < 8; ++j) {
        acc[j] += __shfl_xor(acc[j], 16);
        acc[j] += __shfl_xor(acc[j], 32);
    }

    if (slot == 0) {   // lanes 0..15: add self term, scale, bias, relu, store
        uint4 sv = hsb4[(size_t)n * 16 + cl];
        acc[0] += bf_lo(sv.x); acc[1] += bf_hi(sv.x);
        acc[2] += bf_lo(sv.y); acc[3] += bf_hi(sv.y);
        acc[4] += bf_lo(sv.z); acc[5] += bf_hi(sv.z);
        acc[6] += bf_lo(sv.w); acc[7] += bf_hi(sv.w);
        float d = dis[n];
        const float4* b4 = (const float4*)(bias + cl * 8);
        float4 b0 = b4[0], b1 = b4[1];
        float4 o0, o1;
        o0.x = fmaxf(fmaf(d, acc[0], b0.x), 0.f);
        o0.y = fmaxf(fmaf(d, acc[1], b0.y), 0.f);
        o0.z = fmaxf(fmaf(d, acc[2], b0.z), 0.f);
        o0.w = fmaxf(fmaf(d, acc[3], b0.w), 0.f);
        o1.x = fmaxf(fmaf(d, acc[4], b1.x), 0.f);
        o1.y = fmaxf(fmaf(d, acc[5], b1.y), 0.f);
        o1.z = fmaxf(fmaf(d, acc[6], b1.z), 0.f);
        o1.w = fmaxf(fmaf(d, acc[7], b1.w), 0.f);
        float4* op = (float4*)(out + (size_t)n * HID_C + cl * 8);
        op[0] = o0;
        op[1] = o1;
    }
}

extern "C" void kernel_launch(void* const* d_in, const int* in_sizes, int n_in,
                              void* d_out, int out_size, void* d_ws, size_t ws_size,
                              hipStream_t stream) {
    const float* x    = (const float*)d_in[0];
    const int*   ei   = (const int*)d_in[1];
    const float* w    = (const float*)d_in[2];
    const float* W    = (const float*)d_in[3];
    const float* bias = (const float*)d_in[4];
    float* out = (float*)d_out;

    const int N = in_sizes[0] / IN_C;
    const int E = in_sizes[2];
    const int* row = ei;        // edge_index[0] (source)
    const int* col = ei + E;    // edge_index[1] (destination)
    const int NBK = (N + 255) >> 8;   // 196 buckets of 256 nodes

    // workspace: gcur[256] | ptr[N+1] | dis[N] | wt[16384] ushort
    //            | bedge[NBK*CAP] int2 | sedge[E] int2 | hsb[N*128] ushort
    auto alup = [](size_t v) { return (v + 255) & ~(size_t)255; };
    char* p = (char*)d_ws;
    int*   gcur  = (int*)p;   p += alup(256 * 4);
    int*   ptr   = (int*)p;   p += alup(((size_t)N + 1) * 4);
    float* dis   = (float*)p; p += alup((size_t)N * 4);
    unsigned short* wt = (unsigned short*)p; p += alup(16384 * 2);
    int2*  bedge = (int2*)p;  p += alup((size_t)NBK * CAP * 8);
    int2*  sedge = (int2*)p;  p += alup((size_t)E * 8);
    unsigned short* hsb = (unsigned short*)p; p += alup((size_t)N * HID_C * 2);

    k_prepW<<<16, 256, 0, stream>>>(W, wt, gcur);

    k_passA<<<(E + EPB - 1) / EPB, 256, 0, stream>>>(row, col, w, gcur, bedge, E, NBK);
    k_passB<<<NBK, 256, 0, stream>>>(bedge, gcur, sedge, ptr, dis, E, N, NBK);

    k_gemm_hs<<<(N + 63) / 64, 256, 0, stream>>>(x, wt, dis, hsb, N);

    k_aggregate<<<(N + 3) / 4, 256, 0, stream>>>((const uint4*)hsb, sedge, ptr,
                                                 dis, bias, out, N);
}